// Round 5
// baseline (149.041 us; speedup 1.0000x reference)
//
#include <hip/hip_runtime.h>
#include <math.h>

// B=2048, L=64. out = sum(kl) + (BETA-1)*mean_i(log_qz_i - log_qz_product_i)
// lp2[i,j,l] = lp/ln2 = a2*d^2 + b2, a2 = -0.5/ln2*exp(-lv) < 0
// k3: single-pass sum_j exp2(lp2 - BVAL) (lp2 <= b2 << BVAL for these inputs).
// Horner: lp2 - BVAL = fma(fma(z, a2, c1), z, c0'), c1=-2*a2*m, c0'=a2*m^2+b2-BVAL.
// k2: t2_ij = dot(z^2, a2) + dot(z, c1) + qc2_j with true block max (t2 range wide).

#define NB 2048
#define NL 64
#define NE (NB * NL)
#define BVAL 12.0f

typedef float v2f __attribute__((ext_vector_type(2)));

__device__ __forceinline__ v2f fma2(v2f a, v2f b, v2f c) {
#if __has_builtin(__builtin_elementwise_fma)
  return __builtin_elementwise_fma(a, b, c);
#else
  v2f r;
  r.x = fmaf(a.x, b.x, c.x);
  r.y = fmaf(a.y, b.y, c.y);
  return r;
#endif
}

__device__ __forceinline__ float wredsum(float v) {
#pragma unroll
  for (int o = 32; o; o >>= 1) v += __shfl_xor(v, o, 64);
  return v;
}
__device__ __forceinline__ float wredmax(float v) {
#pragma unroll
  for (int o = 32; o; o >>= 1) v = fmaxf(v, __shfl_xor(v, o, 64));
  return v;
}

// A: coeffs + transposed GEMM arrays + qc2 + kl partials + counter init.
__global__ __launch_bounds__(256) void ka_pre(const float* __restrict__ kl,
                                              const float* __restrict__ zm,
                                              const float* __restrict__ zlv,
                                              float4* __restrict__ PK2,
                                              float* __restrict__ A2T,
                                              float* __restrict__ MA2T,
                                              float* __restrict__ QC2,
                                              float* __restrict__ KLP,
                                              int* __restrict__ CNT) {
  const float INVLN2 = 1.4426950408889634f;
  const float LOG2PI = 1.8378770664093453f;
  int tid = threadIdx.x;
  int e = blockIdx.x * 256 + tid;  // < NE
  int j = e >> 6, l = e & 63;
  float lv = zlv[e], m = zm[e];
  float a2 = -0.5f * INVLN2 * __expf(-lv);
  float b2 = -0.5f * INVLN2 * (lv + LOG2PI);
  float c1 = -2.0f * a2 * m;
  float c0 = fmaf(a2 * m, m, b2);
  PK2[e] = make_float4(a2, c1, c0 - BVAL, 0.0f);
  A2T[l * NB + j] = a2;
  MA2T[l * NB + j] = c1;
  float q = wredsum(c0);
  if (l == 0) QC2[j] = q;
  float ks = wredsum(kl[e]);
  __shared__ float sk[4];
  if (l == 0) sk[tid >> 6] = ks;
  __syncthreads();
  if (tid == 0) KLP[blockIdx.x] = sk[0] + sk[1] + sk[2] + sk[3];
  if (blockIdx.x == 0 && tid == 0) *CNT = 0;
}

// K2 (known-good round-3 form): block LSE of t2 over 8 j-chunks of 256.
// grid (8, 256), 256 thr: thread = one j, 8 i's.
__global__ __launch_bounds__(256) void k2_t(const float* __restrict__ zs,
                                            const float* __restrict__ A2T,
                                            const float* __restrict__ MA2T,
                                            const float* __restrict__ QC2,
                                            float* __restrict__ TPM,
                                            float* __restrict__ TPS) {
  int jc = blockIdx.x;      // 0..7
  int i0 = blockIdx.y * 8;  // i tile base
  int tid = threadIdx.x;
  int w = tid >> 6;
  int j = jc * 256 + tid;
  __shared__ float zsh[64][8];  // [k][r]
  if (tid < 128) {
    int k = tid >> 1, r0 = (tid & 1) * 4;
#pragma unroll
    for (int r = 0; r < 4; ++r) zsh[k][r0 + r] = zs[(i0 + r0 + r) * NL + k];
  }
  __syncthreads();
  float accv[8];
  float q = QC2[j];
#pragma unroll
  for (int r = 0; r < 8; ++r) accv[r] = q;
  for (int k = 0; k < 64; ++k) {
    float av = A2T[k * NB + j];
    float mv = MA2T[k * NB + j];
    const float4* z4 = (const float4*)&zsh[k][0];
    float4 za = z4[0], zb = z4[1];
    float zk[8] = {za.x, za.y, za.z, za.w, zb.x, zb.y, zb.z, zb.w};
#pragma unroll
    for (int r = 0; r < 8; ++r) {
      accv[r] = fmaf(zk[r] * zk[r], av, accv[r]);
      accv[r] = fmaf(zk[r], mv, accv[r]);
    }
  }
  __shared__ float lm[4][8], ls[4][8];
#pragma unroll
  for (int r = 0; r < 8; ++r) {
    float mx = wredmax(accv[r]);
    if ((tid & 63) == 0) lm[w][r] = mx;
  }
  __syncthreads();
  float Mt[8];
#pragma unroll
  for (int r = 0; r < 8; ++r)
    Mt[r] = fmaxf(fmaxf(lm[0][r], lm[1][r]), fmaxf(lm[2][r], lm[3][r]));
#pragma unroll
  for (int r = 0; r < 8; ++r) {
    float ss = wredsum(__builtin_amdgcn_exp2f(accv[r] - Mt[r]));
    if ((tid & 63) == 0) ls[w][r] = ss;
  }
  __syncthreads();
  if (tid == 0) {
#pragma unroll
    for (int r = 0; r < 8; ++r) {
      TPM[(i0 + r) * 8 + jc] = Mt[r];
      TPS[(i0 + r) * 8 + jc] = ls[0][r] + ls[1][r] + ls[2][r] + ls[3][r];
    }
  }
}

// K3: per-(i,l) sum_j exp2(lp2 - BVAL). grid (16 j-chunks, 128 i-tiles of 16),
// 256 thr = 4 waves; wave w takes 32 j's. 16 i's per thread as 8 float2 (pk
// math). No LDS, no sync: each wave stores its own partial slab (64 slabs).
__global__ __launch_bounds__(256) void k3_lse(const float* __restrict__ zs,
                                              const float4* __restrict__ PK2,
                                              float* __restrict__ SP) {
  int jc = blockIdx.x;        // 0..15
  int i0 = blockIdx.y * 16;   // i tile base
  int tid = threadIdx.x;
  int w = tid >> 6, l = tid & 63;
  const float4* p = PK2 + (size_t)(jc * 128 + w * 32) * NL + l;
  v2f zr[8];
#pragma unroll
  for (int r = 0; r < 8; ++r) {
    zr[r].x = zs[(i0 + 2 * r) * NL + l];
    zr[r].y = zs[(i0 + 2 * r + 1) * NL + l];
  }
  v2f S[8];
#pragma unroll
  for (int r = 0; r < 8; ++r) S[r] = (v2f){0.0f, 0.0f};
#pragma unroll 2
  for (int jj = 0; jj < 32; ++jj) {
    float4 c = p[(size_t)jj * NL];
    v2f ca = (v2f){c.x, c.x}, cb = (v2f){c.y, c.y}, cc = (v2f){c.z, c.z};
#pragma unroll
    for (int r = 0; r < 8; ++r) {
      v2f t = fma2(zr[r], ca, cb);
      v2f lp = fma2(t, zr[r], cc);
      v2f e;
      e.x = __builtin_amdgcn_exp2f(lp.x);
      e.y = __builtin_amdgcn_exp2f(lp.y);
      S[r] += e;
    }
  }
  float* sp = SP + (size_t)(jc * 4 + w) * NE;
#pragma unroll
  for (int r = 0; r < 8; ++r) {
    sp[(size_t)(i0 + 2 * r) * NL + l] = S[r].x;
    sp[(size_t)(i0 + 2 * r + 1) * NL + l] = S[r].y;
  }
}

// C: per-i finish (sum 64 slabs -> log2 -> sum_l; merge 8 t-chunks) + last-block
// global reduce. 512 blocks, wave = one i.
__global__ __launch_bounds__(256) void kc_fin(const float* __restrict__ SP,
                                              const float* __restrict__ TPM,
                                              const float* __restrict__ TPS,
                                              const float* __restrict__ KLP,
                                              float* __restrict__ PERB,
                                              int* __restrict__ CNT,
                                              float* __restrict__ out) {
  int tid = threadIdx.x;
  int w = tid >> 6, l = tid & 63;
  int i = blockIdx.x * 4 + w;
  float S = 0.0f;
#pragma unroll 8
  for (int s = 0; s < 64; ++s) S += SP[(size_t)s * NE + (size_t)i * NL + l];
  float val = __builtin_amdgcn_logf(S);  // log2
  float lqp2 = wredsum(val) + 64.0f * BVAL;
  float tm = (l < 8) ? TPM[i * 8 + l] : -1e30f;
  float ts = (l < 8) ? TPS[i * 8 + l] : 0.0f;
  float Mt = wredmax(tm);
  float St = wredsum(ts * __builtin_amdgcn_exp2f(tm - Mt));
  float lqz2 = Mt + __builtin_amdgcn_logf(St);
  __shared__ float sblk[4];
  if (l == 0) sblk[w] = lqz2 - lqp2;
  __syncthreads();
  __shared__ int slast;
  if (tid == 0) {
    float v = sblk[0] + sblk[1] + sblk[2] + sblk[3];
    __hip_atomic_store(&PERB[blockIdx.x], v, __ATOMIC_RELEASE, __HIP_MEMORY_SCOPE_AGENT);
    int old = __hip_atomic_fetch_add(CNT, 1, __ATOMIC_ACQ_REL, __HIP_MEMORY_SCOPE_AGENT);
    slast = (old == 511) ? 1 : 0;
  }
  __syncthreads();
  if (!slast) return;
  float a = 0.0f, b = 0.0f;
  for (int x = tid; x < 512; x += 256) {
    a += KLP[x];
    b += __hip_atomic_load(&PERB[x], __ATOMIC_ACQUIRE, __HIP_MEMORY_SCOPE_AGENT);
  }
  float ra = wredsum(a), rb = wredsum(b);
  __shared__ float sa[4], sb[4];
  if (l == 0) {
    sa[w] = ra;
    sb[w] = rb;
  }
  __syncthreads();
  if (tid == 0) {
    const float LN2 = 0.6931471805599453f;
    float ka = sa[0] + sa[1] + sa[2] + sa[3];
    float kb = sb[0] + sb[1] + sb[2] + sb[3];
    out[0] = ka + 5.0f * LN2 * kb * (1.0f / (float)NB);
  }
}

extern "C" void kernel_launch(void* const* d_in, const int* in_sizes, int n_in,
                              void* d_out, int out_size, void* d_ws, size_t ws_size,
                              hipStream_t stream) {
  const float* kl = (const float*)d_in[0];
  const float* zm = (const float*)d_in[1];
  const float* zlv = (const float*)d_in[2];
  const float* zs = (const float*)d_in[3];
  float* ws = (float*)d_ws;

  float* PK2 = ws;                  // 4*NE
  float* A2T = PK2 + 4 * NE;        // NE
  float* MA2T = A2T + NE;           // NE
  float* QC2 = MA2T + NE;           // NB
  float* SP = QC2 + NB;             // 64*NE (32 MB)
  float* TPM = SP + 64 * (size_t)NE;  // NB*8
  float* TPS = TPM + NB * 8;        // NB*8
  float* KLP = TPS + NB * 8;        // 512
  float* PERB = KLP + 512;          // 512
  int* CNT = (int*)(PERB + 512);    // 1

  ka_pre<<<NE / 256, 256, 0, stream>>>(kl, zm, zlv, (float4*)PK2, A2T, MA2T, QC2,
                                       KLP, CNT);
  k2_t<<<dim3(8, NB / 8), 256, 0, stream>>>(zs, A2T, MA2T, QC2, TPM, TPS);
  k3_lse<<<dim3(16, NB / 16), 256, 0, stream>>>(zs, (const float4*)PK2, SP);
  kc_fin<<<512, 256, 0, stream>>>(SP, TPM, TPS, KLP, PERB, CNT, (float*)d_out);
}

// Round 6
// 141.181 us; speedup vs baseline: 1.0557x; 1.0557x over previous
//
#include <hip/hip_runtime.h>
#include <math.h>

// B=2048, L=64. out = sum(kl) + 5*mean_i(log_qz_i - log_qz_product_i) [BETA-1=5]
// lp2[i,j,l] = lp/ln2 = a2*d^2 + b2, a2 = -0.5/ln2*exp(-lv) < 0
// k3: per-(i,l) sum_j 2^(lp2 - BVAL), Schraudolph fast-exp2:
//   S += as_float( cvt_u32( (lp2-BVAL)*2^23 + MAGIC ) ), MAGIC = 127*2^23 - 486411
//   cvt_u32 saturates negatives to 0 -> underflowed terms contribute +0.0 exactly.
//   Coeffs pre-scaled: a2s=a2*2^23, c1s=-2*a2*m*2^23, C0s=(a2*m^2+b2-BVAL)*2^23+MAGIC
// k2: t2_ij = dot(z^2,a2)+dot(z,c1)+qc2_j, exact exp2 with true block max.

#define NB 2048
#define NL 64
#define NE (NB * NL)
#define BVAL 12.0f
#define EXP_SCALE 8388608.0f        // 2^23
#define EXP_MAGIC 1064866805.0f     // 127*2^23 - 486411 (minimax |rel err| ~2.9%)

typedef float v2f __attribute__((ext_vector_type(2)));

__device__ __forceinline__ v2f fma2(v2f a, v2f b, v2f c) {
#if __has_builtin(__builtin_elementwise_fma)
  return __builtin_elementwise_fma(a, b, c);
#else
  v2f r;
  r.x = fmaf(a.x, b.x, c.x);
  r.y = fmaf(a.y, b.y, c.y);
  return r;
#endif
}

// HW-saturating float->u32 convert (negatives -> 0), then bitcast: fast 2^x tail.
__device__ __forceinline__ float exp2_fast_tail(float p) {
  unsigned u;
  asm("v_cvt_u32_f32 %0, %1" : "=v"(u) : "v"(p));
  return __builtin_bit_cast(float, u);
}

__device__ __forceinline__ float wredsum(float v) {
#pragma unroll
  for (int o = 32; o; o >>= 1) v += __shfl_xor(v, o, 64);
  return v;
}
__device__ __forceinline__ float wredmax(float v) {
#pragma unroll
  for (int o = 32; o; o >>= 1) v = fmaxf(v, __shfl_xor(v, o, 64));
  return v;
}

// A: scaled coeffs for k3, exact transposed arrays + qc2 for k2, kl partials.
__global__ __launch_bounds__(256) void ka_pre(const float* __restrict__ kl,
                                              const float* __restrict__ zm,
                                              const float* __restrict__ zlv,
                                              float4* __restrict__ PK2,
                                              float* __restrict__ A2T,
                                              float* __restrict__ MA2T,
                                              float* __restrict__ QC2,
                                              float* __restrict__ KLP,
                                              int* __restrict__ CNT) {
  const float INVLN2 = 1.4426950408889634f;
  const float LOG2PI = 1.8378770664093453f;
  int tid = threadIdx.x;
  int e = blockIdx.x * 256 + tid;  // < NE
  int j = e >> 6, l = e & 63;
  float lv = zlv[e], m = zm[e];
  float a2 = -0.5f * INVLN2 * __expf(-lv);
  float b2 = -0.5f * INVLN2 * (lv + LOG2PI);
  float c1 = -2.0f * a2 * m;
  float c0 = fmaf(a2 * m, m, b2);
  PK2[e] = make_float4(a2 * EXP_SCALE, c1 * EXP_SCALE,
                       fmaf(c0 - BVAL, EXP_SCALE, EXP_MAGIC), 0.0f);
  A2T[l * NB + j] = a2;
  MA2T[l * NB + j] = c1;
  float q = wredsum(c0);
  if (l == 0) QC2[j] = q;
  float ks = wredsum(kl[e]);
  __shared__ float sk[4];
  if (l == 0) sk[tid >> 6] = ks;
  __syncthreads();
  if (tid == 0) KLP[blockIdx.x] = sk[0] + sk[1] + sk[2] + sk[3];
  if (blockIdx.x == 0 && tid == 0) *CNT = 0;
}

// K2 (proven round-3 form): block LSE of t2 over 8 j-chunks of 256.
__global__ __launch_bounds__(256) void k2_t(const float* __restrict__ zs,
                                            const float* __restrict__ A2T,
                                            const float* __restrict__ MA2T,
                                            const float* __restrict__ QC2,
                                            float* __restrict__ TPM,
                                            float* __restrict__ TPS) {
  int jc = blockIdx.x;      // 0..7
  int i0 = blockIdx.y * 8;  // i tile base
  int tid = threadIdx.x;
  int w = tid >> 6;
  int j = jc * 256 + tid;
  __shared__ float zsh[64][8];  // [k][r]
  if (tid < 128) {
    int k = tid >> 1, r0 = (tid & 1) * 4;
#pragma unroll
    for (int r = 0; r < 4; ++r) zsh[k][r0 + r] = zs[(i0 + r0 + r) * NL + k];
  }
  __syncthreads();
  float accv[8];
  float q = QC2[j];
#pragma unroll
  for (int r = 0; r < 8; ++r) accv[r] = q;
  for (int k = 0; k < 64; ++k) {
    float av = A2T[k * NB + j];
    float mv = MA2T[k * NB + j];
    const float4* z4 = (const float4*)&zsh[k][0];
    float4 za = z4[0], zb = z4[1];
    float zk[8] = {za.x, za.y, za.z, za.w, zb.x, zb.y, zb.z, zb.w};
#pragma unroll
    for (int r = 0; r < 8; ++r) {
      accv[r] = fmaf(zk[r] * zk[r], av, accv[r]);
      accv[r] = fmaf(zk[r], mv, accv[r]);
    }
  }
  __shared__ float lm[4][8], ls[4][8];
#pragma unroll
  for (int r = 0; r < 8; ++r) {
    float mx = wredmax(accv[r]);
    if ((tid & 63) == 0) lm[w][r] = mx;
  }
  __syncthreads();
  float Mt[8];
#pragma unroll
  for (int r = 0; r < 8; ++r)
    Mt[r] = fmaxf(fmaxf(lm[0][r], lm[1][r]), fmaxf(lm[2][r], lm[3][r]));
#pragma unroll
  for (int r = 0; r < 8; ++r) {
    float ss = wredsum(__builtin_amdgcn_exp2f(accv[r] - Mt[r]));
    if ((tid & 63) == 0) ls[w][r] = ss;
  }
  __syncthreads();
  if (tid == 0) {
#pragma unroll
    for (int r = 0; r < 8; ++r) {
      TPM[(i0 + r) * 8 + jc] = Mt[r];
      TPS[(i0 + r) * 8 + jc] = ls[0][r] + ls[1][r] + ls[2][r] + ls[3][r];
    }
  }
}

// K3: per-(i,l) sum_j 2^(lp2-BVAL) via fast-exp2. grid (8 jc, 64 i-tiles of 32),
// 256 thr = 4 waves; wave w: 64 j's. 32 i's/thread as 16 v2f (pk math).
// Inner: 3 v_pk_fma + 2 v_cvt_u32 + 1 v_pk_add = 5 cyc/elem issue floor.
// Block-combine 4 waves via LDS -> one slab per jc (8 slabs, 4 MB, L2-resident).
__global__ __launch_bounds__(256) void k3_lse(const float* __restrict__ zs,
                                              const float4* __restrict__ PK2,
                                              float* __restrict__ SP) {
  int jc = blockIdx.x;       // 0..7
  int i0 = blockIdx.y * 32;  // i tile base
  int tid = threadIdx.x;
  int w = tid >> 6, l = tid & 63;
  const float4* p = PK2 + (size_t)(jc * 256 + w * 64) * NL + l;
  v2f zr[16];
#pragma unroll
  for (int r = 0; r < 16; ++r) {
    zr[r].x = zs[(i0 + 2 * r) * NL + l];
    zr[r].y = zs[(i0 + 2 * r + 1) * NL + l];
  }
  v2f S[16];
#pragma unroll
  for (int r = 0; r < 16; ++r) S[r] = (v2f){0.0f, 0.0f};
#pragma unroll 2
  for (int jj = 0; jj < 64; ++jj) {
    float4 c = p[(size_t)jj * NL];
    v2f ca = (v2f){c.x, c.x}, cb = (v2f){c.y, c.y}, cc = (v2f){c.z, c.z};
#pragma unroll
    for (int r = 0; r < 16; ++r) {
      v2f t = fma2(zr[r], ca, cb);
      v2f pa = fma2(t, zr[r], cc);
      v2f e;
      e.x = exp2_fast_tail(pa.x);
      e.y = exp2_fast_tail(pa.y);
      S[r] += e;
    }
  }
  __shared__ float lss[4][32][64];  // 32 KB
#pragma unroll
  for (int r = 0; r < 16; ++r) {
    lss[w][2 * r][l] = S[r].x;
    lss[w][2 * r + 1][l] = S[r].y;
  }
  __syncthreads();
  for (int pp = tid; pp < 2048; pp += 256) {
    int ii = pp >> 6, ll = pp & 63;
    float Sc = lss[0][ii][ll] + lss[1][ii][ll] + lss[2][ii][ll] + lss[3][ii][ll];
    SP[(size_t)jc * NE + (size_t)(i0 + ii) * NL + ll] = Sc;
  }
}

// C: per-i finish (sum 8 slabs -> log2 -> sum_l + 64*BVAL; merge 8 t-chunks) +
// last-block global reduce. 512 blocks, wave = one i.
__global__ __launch_bounds__(256) void kc_fin(const float* __restrict__ SP,
                                              const float* __restrict__ TPM,
                                              const float* __restrict__ TPS,
                                              const float* __restrict__ KLP,
                                              float* __restrict__ PERB,
                                              int* __restrict__ CNT,
                                              float* __restrict__ out) {
  int tid = threadIdx.x;
  int w = tid >> 6, l = tid & 63;
  int i = blockIdx.x * 4 + w;
  float S = 0.0f;
#pragma unroll
  for (int s = 0; s < 8; ++s) S += SP[(size_t)s * NE + (size_t)i * NL + l];
  float val = __builtin_amdgcn_logf(S);  // log2
  float lqp2 = wredsum(val) + 64.0f * BVAL;
  float tm = (l < 8) ? TPM[i * 8 + l] : -1e30f;
  float ts = (l < 8) ? TPS[i * 8 + l] : 0.0f;
  float Mt = wredmax(tm);
  float St = wredsum(ts * __builtin_amdgcn_exp2f(tm - Mt));
  float lqz2 = Mt + __builtin_amdgcn_logf(St);
  __shared__ float sblk[4];
  if (l == 0) sblk[w] = lqz2 - lqp2;
  __syncthreads();
  __shared__ int slast;
  if (tid == 0) {
    float v = sblk[0] + sblk[1] + sblk[2] + sblk[3];
    __hip_atomic_store(&PERB[blockIdx.x], v, __ATOMIC_RELEASE, __HIP_MEMORY_SCOPE_AGENT);
    int old = __hip_atomic_fetch_add(CNT, 1, __ATOMIC_ACQ_REL, __HIP_MEMORY_SCOPE_AGENT);
    slast = (old == 511) ? 1 : 0;
  }
  __syncthreads();
  if (!slast) return;
  float a = 0.0f, b = 0.0f;
  for (int x = tid; x < 512; x += 256) {
    a += KLP[x];
    b += __hip_atomic_load(&PERB[x], __ATOMIC_ACQUIRE, __HIP_MEMORY_SCOPE_AGENT);
  }
  float ra = wredsum(a), rb = wredsum(b);
  __shared__ float sa[4], sb[4];
  if (l == 0) {
    sa[w] = ra;
    sb[w] = rb;
  }
  __syncthreads();
  if (tid == 0) {
    const float LN2 = 0.6931471805599453f;
    float ka = sa[0] + sa[1] + sa[2] + sa[3];
    float kb = sb[0] + sb[1] + sb[2] + sb[3];
    out[0] = ka + 5.0f * LN2 * kb * (1.0f / (float)NB);
  }
}

extern "C" void kernel_launch(void* const* d_in, const int* in_sizes, int n_in,
                              void* d_out, int out_size, void* d_ws, size_t ws_size,
                              hipStream_t stream) {
  const float* kl = (const float*)d_in[0];
  const float* zm = (const float*)d_in[1];
  const float* zlv = (const float*)d_in[2];
  const float* zs = (const float*)d_in[3];
  float* ws = (float*)d_ws;

  float* PK2 = ws;                  // 4*NE (2 MB)
  float* A2T = PK2 + 4 * NE;        // NE
  float* MA2T = A2T + NE;           // NE
  float* QC2 = MA2T + NE;           // NB
  float* SP = QC2 + NB;             // 8*NE (4 MB)
  float* TPM = SP + 8 * NE;         // NB*8
  float* TPS = TPM + NB * 8;        // NB*8
  float* KLP = TPS + NB * 8;        // 512
  float* PERB = KLP + 512;          // 512
  int* CNT = (int*)(PERB + 512);    // 1   (total ~7.2 MB dirty)

  ka_pre<<<NE / 256, 256, 0, stream>>>(kl, zm, zlv, (float4*)PK2, A2T, MA2T, QC2,
                                       KLP, CNT);
  k2_t<<<dim3(8, NB / 8), 256, 0, stream>>>(zs, A2T, MA2T, QC2, TPM, TPS);
  k3_lse<<<dim3(8, NB / 32), 256, 0, stream>>>(zs, (const float4*)PK2, SP);
  kc_fin<<<512, 256, 0, stream>>>(SP, TPM, TPS, KLP, PERB, CNT, (float*)d_out);
}